// Round 1
// baseline (254.344 us; speedup 1.0000x reference)
//
#include <hip/hip_runtime.h>

#define BS 2
#define TS 128
#define DM 512
#define NH 8
#define DH 64

// fp32 workspace layout (element offsets)
#define SEG (BS*NH*TS*DH)        // 131072
#define OFS_K1 0
#define OFS_K2 (1*SEG)
#define OFS_Q  (2*SEG)
#define OFS_VA (3*SEG)
#define OFS_VB (4*SEG)
#define OFS_Z  (5*SEG)           // z stored [b][p][n][h] = row-major (256 x 512)

// ---------------------------------------------------------------------------
// Kernel A: the 5 projections  k1,k2,q,va,vb : [b][n][s][h] each
// block = (proj, b, n, s-tile of 4); 256 threads = 4 s x 64 h
// ---------------------------------------------------------------------------
__global__ __launch_bounds__(256) void proj_kernel(
    const float* __restrict__ x,   const float* __restrict__ Wk1,
    const float* __restrict__ Wk2, const float* __restrict__ Wq,
    const float* __restrict__ Wv12,const float* __restrict__ bk1,
    const float* __restrict__ bk2, const float* __restrict__ bq,
    float* __restrict__ ws)
{
  int t = blockIdx.x;
  int stile = t & 31; t >>= 5;
  int n = t & 7;      t >>= 3;
  int b = t & 1;      t >>= 1;
  int proj = t;                       // 0..4
  int h  = threadIdx.x & 63;
  int sl = threadIdx.x >> 6;
  int s  = stile * 4 + sl;

  const float* W; const float* bias = nullptr; float* outp;
  switch (proj) {
    case 0:  W = Wk1 + n*DM*DH;             bias = bk1; outp = ws + OFS_K1; break;
    case 1:  W = Wk2 + n*DM*DH;             bias = bk2; outp = ws + OFS_K2; break;
    case 2:  W = Wq  + n*DM*DH;             bias = bq;  outp = ws + OFS_Q;  break;
    case 3:  W = Wv12 + n*2*DM*DH;                      outp = ws + OFS_VA; break;
    default: W = Wv12 + n*2*DM*DH + DM*DH;              outp = ws + OFS_VB; break;
  }

  __shared__ float xs[4][DM];
  for (int i = threadIdx.x; i < 4*DM; i += 256)
    xs[i >> 9][i & 511] = x[(size_t)(b*TS + stile*4 + (i >> 9))*DM + (i & 511)];
  __syncthreads();

  float acc = 0.f;
  #pragma unroll 8
  for (int d = 0; d < DM; ++d)
    acc = fmaf(xs[sl][d], W[d*DH + h], acc);   // W read coalesced across h
  if (bias) acc += bias[n*DH + h];
  outp[((b*NH + n)*TS + s)*DH + h] = acc;
}

// ---------------------------------------------------------------------------
// Kernel B: per (b,n,q): scores over valid triangle s<t<q, softmax (sink=0
// contribution), marginal-weighted sums of va/vb -> z[b][q][n][h]
// 256 threads. LDS ~62.7 KB (<=64KB static limit).
// ---------------------------------------------------------------------------
__global__ __launch_bounds__(256) void attn_kernel(
    const float* __restrict__ ws, const float* __restrict__ bv12,
    float* __restrict__ z)
{
  int t = blockIdx.x;
  int q = t & 127; t >>= 7;
  int n = t & 7;   t >>= 3;
  int b = t;
  int tid = threadIdx.x;

  float* zrow = z + ((b*TS + q)*NH + n)*DH;
  if (q < 2) {                      // all scores masked; sink takes weight 1, vf(sink)=0
    if (tid < DH) zrow[tid] = 0.f;
    return;
  }

  const float* k1 = ws + OFS_K1 + (b*NH + n)*TS*DH;
  const float* k2 = ws + OFS_K2 + (b*NH + n)*TS*DH;
  const float* qv = ws + OFS_Q  + ((b*NH + n)*TS + q)*DH;
  const float* va = ws + OFS_VA + (b*NH + n)*TS*DH;
  const float* vb = ws + OFS_VB + (b*NH + n)*TS*DH;

  __shared__ __align__(16) float a_s[TS][68];   // k1 * q_vec, padded (68: 16B-aligned, conflict-free)
  __shared__ __align__(16) float k2s[32][68];   // current t-strip of k2
  __shared__ float ps[TS][33];                  // p for current t-strip
  __shared__ float rs[TS], cs[TS];              // row / col marginals
  __shared__ float wq[DH];
  __shared__ float zpart[4][DH];
  __shared__ float dshared;

  if (tid < DH) wq[tid] = qv[tid];
  if (tid < TS) { rs[tid] = 0.f; cs[tid] = 0.f; }
  __syncthreads();
  for (int i = tid; i < TS*DH; i += 256) {      // stage a = k1 (.) wq, all 128 rows
    int s = i >> 6, h = i & 63;
    a_s[s][h] = k1[i] * wq[h];
  }

  const float inv_dh = 1.0f / DH;
  for (int t0 = 0; t0 < q; t0 += 32) {
    __syncthreads();                            // prior reduce done / a_s staged
    for (int i = tid; i < 32*DH; i += 256) {    // stage k2 strip (always in-bounds: t0<=96)
      int tt = i >> 6, h = i & 63;
      k2s[tt][h] = k2[(t0 + tt)*DH + h];
    }
    __syncthreads();

    // 2x2 register tiles over (s,t) rectangle; skip fully-masked tiles
    for (int slot = tid; slot < 64*16; slot += 256) {
      int stt = slot & 15;                      // t-tile in strip (fast -> conflict-free k2s reads)
      int sst = slot >> 4;                      // s-tile 0..63
      int tb = t0 + 2*stt;
      if (tb >= q) continue;
      int tcap = min(tb + 1, q - 1);
      int sb = 2*sst;
      if (sb >= tcap) continue;

      const float4* a0 = (const float4*)a_s[sb];
      const float4* a1 = (const float4*)a_s[sb + 1];
      const float4* b0 = (const float4*)k2s[2*stt];
      const float4* b1 = (const float4*)k2s[2*stt + 1];
      float acc00=0.f, acc01=0.f, acc10=0.f, acc11=0.f;
      #pragma unroll
      for (int hc = 0; hc < 16; ++hc) {
        float4 av0=a0[hc], av1=a1[hc], bv0=b0[hc], bv1=b1[hc];
        acc00 += av0.x*bv0.x + av0.y*bv0.y + av0.z*bv0.z + av0.w*bv0.w;
        acc01 += av0.x*bv1.x + av0.y*bv1.y + av0.z*bv1.z + av0.w*bv1.w;
        acc10 += av1.x*bv0.x + av1.y*bv0.y + av1.z*bv0.z + av1.w*bv0.w;
        acc11 += av1.x*bv1.x + av1.y*bv1.y + av1.z*bv1.z + av1.w*bv1.w;
      }
      int lt0 = 2*stt, lt1 = lt0 + 1;
      int tg0 = tb, tg1 = tb + 1;
      // scores tiny (~0.1) -> exp without max-subtraction == reference softmax
      ps[sb  ][lt0] = (sb   < tg0 && tg0 < q) ? expf(acc00 * inv_dh) : 0.f;
      ps[sb  ][lt1] = (sb   < tg1 && tg1 < q) ? expf(acc01 * inv_dh) : 0.f;
      ps[sb+1][lt0] = (sb+1 < tg0 && tg0 < q) ? expf(acc10 * inv_dh) : 0.f;
      ps[sb+1][lt1] = (sb+1 < tg1 && tg1 < q) ? expf(acc11 * inv_dh) : 0.f;
    }
    __syncthreads();

    if (tid < TS) {                             // row marginals
      int s = tid;
      int tlo = max(s + 1, t0), thi = min(q, t0 + 32);
      float r = 0.f;
      for (int tt = tlo; tt < thi; ++tt) r += ps[s][tt - t0];
      rs[s] += r;
    } else if (tid < TS + 32) {                 // col marginals
      int ttl = tid - TS;
      int tg = t0 + ttl;
      if (tg < q) {
        float c = 0.f;
        for (int s2 = 0; s2 < tg; ++s2) c += ps[s2][ttl];
        cs[tg] += c;
      }
    }
  }
  __syncthreads();

  if (tid < 64) {                               // denom = sum(p); exp(SINK)==0 in fp32
    float v = rs[tid] + rs[tid + 64];
    for (int off = 32; off > 0; off >>= 1) v += __shfl_down(v, off, 64);
    if (tid == 0) dshared = v;
  }
  __syncthreads();

  int g = tid >> 6, h = tid & 63;               // z = (rs.va + cs.vb)/D + b_V12
  float acc = 0.f;
  for (int s = g; s < q; s += 4)   acc = fmaf(rs[s],  va[s*DH + h],  acc);
  for (int tt = g; tt < q; tt += 4) acc = fmaf(cs[tt], vb[tt*DH + h], acc);
  zpart[g][h] = acc;
  __syncthreads();
  if (tid < DH) {
    float D = dshared;
    float zv = (zpart[0][tid] + zpart[1][tid] + zpart[2][tid] + zpart[3][tid]) / D;
    zrow[tid] = zv + bv12[n*DH + tid];          // b_V12 weight = sum(p)/D = 1
  }
}

// ---------------------------------------------------------------------------
// Kernel C: out(256x512) = Z(256x512) @ W_O(512x512) + b_O
// block = 4 rows; 256 threads, each 4 rows x 2 cols
// ---------------------------------------------------------------------------
__global__ __launch_bounds__(256) void out_kernel(
    const float* __restrict__ zin, const float* __restrict__ Wo,
    const float* __restrict__ bo, float* __restrict__ out)
{
  int row0 = blockIdx.x * 4;
  __shared__ float zs[4][512];
  for (int i = threadIdx.x; i < 4*512; i += 256)
    zs[i >> 9][i & 511] = zin[(size_t)row0*512 + i];
  __syncthreads();

  int d = threadIdx.x;
  float acc[4][2] = {};
  for (int k = 0; k < 512; ++k) {
    float w0 = Wo[k*512 + d];
    float w1 = Wo[k*512 + d + 256];
    #pragma unroll
    for (int r = 0; r < 4; ++r) {
      acc[r][0] = fmaf(zs[r][k], w0, acc[r][0]);
      acc[r][1] = fmaf(zs[r][k], w1, acc[r][1]);
    }
  }
  #pragma unroll
  for (int r = 0; r < 4; ++r) {
    out[(size_t)(row0 + r)*512 + d]       = acc[r][0] + bo[d];
    out[(size_t)(row0 + r)*512 + d + 256] = acc[r][1] + bo[d + 256];
  }
}

extern "C" void kernel_launch(void* const* d_in, const int* in_sizes, int n_in,
                              void* d_out, int out_size, void* d_ws, size_t ws_size,
                              hipStream_t stream)
{
  const float* x    = (const float*)d_in[0];
  const float* Wk1  = (const float*)d_in[1];
  const float* Wk2  = (const float*)d_in[2];
  const float* Wq   = (const float*)d_in[3];
  const float* Wv12 = (const float*)d_in[4];
  const float* Wo   = (const float*)d_in[5];
  const float* bk1  = (const float*)d_in[6];
  const float* bk2  = (const float*)d_in[7];
  const float* bq   = (const float*)d_in[8];
  const float* bv12 = (const float*)d_in[9];
  const float* bo   = (const float*)d_in[10];
  float* out = (float*)d_out;
  float* ws  = (float*)d_ws;   // needs 6*SEG*4 = 3 MB

  proj_kernel<<<5*BS*NH*32, 256, 0, stream>>>(x, Wk1, Wk2, Wq, Wv12, bk1, bk2, bq, ws);
  attn_kernel<<<BS*NH*TS, 256, 0, stream>>>(ws, bv12, ws + OFS_Z);
  out_kernel<<<BS*TS/4, 256, 0, stream>>>(ws + OFS_Z, Wo, bo, out);
}

// Round 2
// 244.705 us; speedup vs baseline: 1.0394x; 1.0394x over previous
//
#include <hip/hip_runtime.h>

#define BS 2
#define TS 128
#define DM 512
#define NH 8
#define DH 64
#define BN (BS*NH)            // 16
#define NPAIR 8128            // C(128,2)
#define PT 512                // pairs per attn block
#define NTILE 16              // ceil(NPAIR/PT)
#define PW 68                 // partial row width (64 z + D + pad)

typedef __attribute__((ext_vector_type(8))) short short8;
typedef __attribute__((ext_vector_type(4))) float floatx4;

// ws layout (float element offsets)
#define SEG (BN*TS*DH)                  // 131072
#define OFS_K1  0
#define OFS_K2  SEG
#define OFS_QB  (2*SEG)                 // bf16 Q, occupies SEG/2 floats
#define OFS_VAT (2*SEG + SEG/2)         // va transposed [bn][h][s]
#define OFS_VBT (OFS_VAT + SEG)
#define OFS_Z   (OFS_VBT + SEG)         // z [b][q][n][h] = 256x512 fp32
#define OFS_PART (OFS_Z + SEG)          // BN*NTILE * TS * PW floats (~8.9MB)

__device__ __forceinline__ short f2bf(float x) {
  unsigned u = __float_as_uint(x);
  u += 0x7fff + ((u >> 16) & 1);        // round-to-nearest-even
  return (short)(u >> 16);
}

// ---------------------------------------------------------------------------
// Kernel A: 5 projections. k1,k2 fp32 [bn][s][h]; q bf16 [bn][s][h];
// va,vb fp32 TRANSPOSED [bn][h][s] (consumed h-major by attn VG build).
// ---------------------------------------------------------------------------
__global__ __launch_bounds__(256) void proj_kernel(
    const float* __restrict__ x,   const float* __restrict__ Wk1,
    const float* __restrict__ Wk2, const float* __restrict__ Wq,
    const float* __restrict__ Wv12,const float* __restrict__ bk1,
    const float* __restrict__ bk2, const float* __restrict__ bq,
    float* __restrict__ ws)
{
  int t = blockIdx.x;
  int stile = t & 31; t >>= 5;
  int n = t & 7;      t >>= 3;
  int b = t & 1;      t >>= 1;
  int proj = t;                       // 0..4
  int h  = threadIdx.x & 63;
  int sl = threadIdx.x >> 6;
  int s  = stile * 4 + sl;
  int bn = b*NH + n;

  const float* W;
  switch (proj) {
    case 0:  W = Wk1 + n*DM*DH;  break;
    case 1:  W = Wk2 + n*DM*DH;  break;
    case 2:  W = Wq  + n*DM*DH;  break;
    case 3:  W = Wv12 + n*2*DM*DH;  break;
    default: W = Wv12 + n*2*DM*DH + DM*DH;  break;
  }

  __shared__ float xs[4][DM];
  for (int i = threadIdx.x; i < 4*DM; i += 256)
    xs[i >> 9][i & 511] = x[(size_t)(b*TS + stile*4 + (i >> 9))*DM + (i & 511)];
  __syncthreads();

  float acc = 0.f;
  #pragma unroll 8
  for (int d = 0; d < DM; ++d)
    acc = fmaf(xs[sl][d], W[d*DH + h], acc);

  switch (proj) {
    case 0: ws[OFS_K1 + (bn*TS + s)*DH + h] = acc + bk1[n*DH + h]; break;
    case 1: ws[OFS_K2 + (bn*TS + s)*DH + h] = acc + bk2[n*DH + h]; break;
    case 2: ((unsigned short*)(ws + OFS_QB))[(bn*TS + s)*DH + h] =
              (unsigned short)f2bf(acc + bq[n*DH + h]); break;
    case 3: ws[OFS_VAT + (bn*DH + h)*TS + s] = acc; break;
    default: ws[OFS_VBT + (bn*DH + h)*TS + s] = acc; break;
  }
}

// ---------------------------------------------------------------------------
// Kernel B: pair-domain trittention core.
// Block = (bn, pair-tile of 512). 256 threads = 4 waves.
// Per 128-pair sub-tile: G=k1.k2 (bf16 LDS) ; S = G @ Q^T via MFMA (q in two
// halves of 64) ; P = exp(S/64) masked t<q -> Pt LDS ; Z += Pt @ VG (VG has a
// ones-column at h=64 producing the softmax denominator). Partials -> ws.
// ---------------------------------------------------------------------------
__global__ __launch_bounds__(256) void attn_kernel(
    const float* __restrict__ ws, float* __restrict__ part)
{
  int bn   = blockIdx.x >> 4;
  int tile = blockIdx.x & 15;
  int tid = threadIdx.x;
  int wv = tid >> 6, ln = tid & 63, q4 = ln >> 4, l15 = ln & 15;

  const float* k1 = ws + OFS_K1 + bn*TS*DH;
  const float* k2 = ws + OFS_K2 + bn*TS*DH;
  const unsigned short* qb = (const unsigned short*)(ws + OFS_QB) + bn*TS*DH;
  const float* vaT = ws + OFS_VAT + bn*DH*TS;
  const float* vbT = ws + OFS_VBT + bn*DH*TS;
  float* myp = part + (bn*NTILE + tile)*TS*PW;

  __shared__ __align__(16) short Gs[128][72];    // 144B rows: 16B-aligned, 2-way banks
  __shared__ __align__(16) short VGt[80][136];   // [h][p], 272B rows
  __shared__ __align__(16) short Pt[64][136];    // [q_local][p]
  __shared__ int spair[PT];
  __shared__ int tpair[PT];

  for (int i = tid; i < PT; i += 256) {          // decode pair index -> (s,t)
    int gi = tile*PT + i;
    float f = sqrtf(8.0f*(float)gi + 1.0f);
    int t = (int)((1.0f + f) * 0.5f);
    while (t*(t-1)/2 > gi) --t;
    while ((t+1)*t/2 <= gi) ++t;
    spair[i] = gi - t*(t-1)/2;
    tpair[i] = t;                                 // t >= TS marks padding pair
  }

  floatx4 accZ[2][5];
  #pragma unroll
  for (int a = 0; a < 2; ++a)
    #pragma unroll
    for (int c = 0; c < 5; ++c) accZ[a][c] = (floatx4){0.f,0.f,0.f,0.f};

  for (int st = 0; st < 4; ++st) {
    __syncthreads();                              // prev readers of Gs/VGt done
    {                                             // build G (p-uniform per wave)
      int h = tid & 63, p0 = tid >> 6;
      for (int j = 0; j < 32; ++j) {
        int p = p0*32 + j;
        int pg = st*128 + p;
        int s = spair[pg], t = tpair[pg];
        float g = (t < TS) ? k1[s*DH + h] * k2[t*DH + h] : 0.f;
        Gs[p][h] = f2bf(g);
      }
    }
    for (int jj = 0; jj < 40; ++jj) {             // build VGt [h][p] + ones row
      int idx = jj*256 + tid;
      int r = idx >> 7, p = idx & 127;
      int pg = st*128 + p;
      int s = spair[pg], t = tpair[pg];
      float v;
      if (r < 64)      v = (t < TS) ? (vaT[r*TS + s] + vbT[r*TS + t]) : 0.f;
      else             v = (r == 64) ? 1.0f : 0.f;
      VGt[r][p] = f2bf(v);
    }
    __syncthreads();

    for (int qh = 0; qh < 2; ++qh) {
      int q0 = qh*64;
      if (qh) __syncthreads();                    // Pt reuse between halves

      // GEMM1: S(128p x 64q) = G @ Q^T ; wave wv owns M-tiles {2wv,2wv+1}
      short8 afr[2][2];
      #pragma unroll
      for (int mi = 0; mi < 2; ++mi) {
        int m = (2*wv + mi)*16 + l15;
        #pragma unroll
        for (int ks = 0; ks < 2; ++ks)
          afr[mi][ks] = *(const short8*)&Gs[m][q4*8 + ks*32];
      }
      for (int nt = 0; nt < 4; ++nt) {
        int qg = q0 + nt*16 + l15;
        short8 bfr[2];
        #pragma unroll
        for (int ks = 0; ks < 2; ++ks)
          bfr[ks] = *(const short8*)(qb + qg*DH + q4*8 + ks*32);
        #pragma unroll
        for (int mi = 0; mi < 2; ++mi) {
          floatx4 c = (floatx4){0.f,0.f,0.f,0.f};
          c = __builtin_amdgcn_mfma_f32_16x16x32_bf16(afr[mi][0], bfr[0], c, 0,0,0);
          c = __builtin_amdgcn_mfma_f32_16x16x32_bf16(afr[mi][1], bfr[1], c, 0,0,0);
          #pragma unroll
          for (int rg = 0; rg < 4; ++rg) {        // exp + causal mask + transpose-store
            int p = (2*wv + mi)*16 + q4*4 + rg;
            int t = tpair[st*128 + p];
            float e = (t < qg) ? __expf(c[rg] * 0.015625f) : 0.f;
            Pt[nt*16 + l15][p] = f2bf(e);
          }
        }
      }
      __syncthreads();

      // GEMM2: Z(64q x 80) += Pt @ VG ; wave wv owns M-tile wv
      short8 pfr[4];
      int m = wv*16 + l15;
      #pragma unroll
      for (int ks = 0; ks < 4; ++ks)
        pfr[ks] = *(const short8*)&Pt[m][q4*8 + ks*32];
      #pragma unroll
      for (int nh = 0; nh < 5; ++nh) {
        int n = nh*16 + l15;
        floatx4 c = accZ[qh][nh];
        #pragma unroll
        for (int ks = 0; ks < 4; ++ks) {
          short8 b = *(const short8*)&VGt[n][q4*8 + ks*32];
          c = __builtin_amdgcn_mfma_f32_16x16x32_bf16(pfr[ks], b, c, 0,0,0);
        }
        accZ[qh][nh] = c;
      }
    }
  }

  // write partial Z (+ D column) for this tile
  #pragma unroll
  for (int qh = 0; qh < 2; ++qh)
    #pragma unroll
    for (int nh = 0; nh < 5; ++nh)
      #pragma unroll
      for (int rg = 0; rg < 4; ++rg) {
        int q = qh*64 + wv*16 + q4*4 + rg;
        if (nh < 4)          myp[q*PW + nh*16 + l15] = accZ[qh][nh][rg];
        else if (l15 == 0)   myp[q*PW + 64]          = accZ[qh][nh][rg];
      }
}

// ---------------------------------------------------------------------------
// Kernel C: reduce 16 tile-partials, normalize by D, add b_V12, emit z
// in [b][q][n][h] layout. Block = (bn,q), 64 threads.
// ---------------------------------------------------------------------------
__global__ __launch_bounds__(64) void norm_kernel(
    const float* __restrict__ part, const float* __restrict__ bv12,
    float* __restrict__ z)
{
  int q  = blockIdx.x & 127;
  int bn = blockIdx.x >> 7;
  int h = threadIdx.x;
  const float* base = part + (size_t)(bn*NTILE)*TS*PW + q*PW;
  float accZ = 0.f, accD = 0.f;
  for (int t = 0; t < NTILE; ++t) {
    accZ += base[t*TS*PW + h];
    accD += base[t*TS*PW + 64];
  }
  int b = bn >> 3, n = bn & 7;
  float zv = (q < 2) ? 0.f : (accZ / accD + bv12[n*DH + h]);
  z[((b*TS + q)*NH + n)*DH + h] = zv;
}

// ---------------------------------------------------------------------------
// Kernel D: out(256x512) = Z(256x512) @ W_O(512x512) + b_O
// ---------------------------------------------------------------------------
__global__ __launch_bounds__(256) void out_kernel(
    const float* __restrict__ zin, const float* __restrict__ Wo,
    const float* __restrict__ bo, float* __restrict__ out)
{
  int row0 = blockIdx.x * 4;
  __shared__ float zs[4][512];
  for (int i = threadIdx.x; i < 4*512; i += 256)
    zs[i >> 9][i & 511] = zin[(size_t)row0*512 + i];
  __syncthreads();

  int d = threadIdx.x;
  float acc[4][2] = {};
  for (int k = 0; k < 512; ++k) {
    float w0 = Wo[k*512 + d];
    float w1 = Wo[k*512 + d + 256];
    #pragma unroll
    for (int r = 0; r < 4; ++r) {
      acc[r][0] = fmaf(zs[r][k], w0, acc[r][0]);
      acc[r][1] = fmaf(zs[r][k], w1, acc[r][1]);
    }
  }
  #pragma unroll
  for (int r = 0; r < 4; ++r) {
    out[(size_t)(row0 + r)*512 + d]       = acc[r][0] + bo[d];
    out[(size_t)(row0 + r)*512 + d + 256] = acc[r][1] + bo[d + 256];
  }
}

extern "C" void kernel_launch(void* const* d_in, const int* in_sizes, int n_in,
                              void* d_out, int out_size, void* d_ws, size_t ws_size,
                              hipStream_t stream)
{
  const float* x    = (const float*)d_in[0];
  const float* Wk1  = (const float*)d_in[1];
  const float* Wk2  = (const float*)d_in[2];
  const float* Wq   = (const float*)d_in[3];
  const float* Wv12 = (const float*)d_in[4];
  const float* Wo   = (const float*)d_in[5];
  const float* bk1  = (const float*)d_in[6];
  const float* bk2  = (const float*)d_in[7];
  const float* bq   = (const float*)d_in[8];
  const float* bv12 = (const float*)d_in[9];
  const float* bo   = (const float*)d_in[10];
  float* out = (float*)d_out;
  float* ws  = (float*)d_ws;    // needs (OFS_PART + BN*NTILE*TS*PW)*4 ≈ 11.8 MB

  proj_kernel<<<5*BS*NH*32, 256, 0, stream>>>(x, Wk1, Wk2, Wq, Wv12, bk1, bk2, bq, ws);
  attn_kernel<<<BN*NTILE, 256, 0, stream>>>(ws, ws + OFS_PART);
  norm_kernel<<<BN*TS, 64, 0, stream>>>(ws + OFS_PART, bv12, ws + OFS_Z);
  out_kernel<<<BS*TS/4, 256, 0, stream>>>(ws + OFS_Z, Wo, bo, out);
}

// Round 3
// 161.496 us; speedup vs baseline: 1.5749x; 1.5152x over previous
//
#include <hip/hip_runtime.h>

#define BS 2
#define TS 128
#define DM 512
#define NH 8
#define DH 64
#define BN (BS*NH)            // 16

typedef __attribute__((ext_vector_type(8))) short short8;
typedef __attribute__((ext_vector_type(4))) float floatx4;

// ws layout (float element offsets). Total 5.5*SEG*4B = 2.88 MB.
#define SEG (BN*TS*DH)                  // 131072
#define OFS_K1  0                       // fp32 [bn][s][h] (+bias)
#define OFS_Q   SEG                     // fp32 [bn][s][h] (+bias)
#define OFS_VA  (2*SEG)                 // fp32 [bn][s][h]
#define OFS_VB  (3*SEG)                 // fp32 [bn][s][h]
#define OFS_K2B (4*SEG)                 // bf16 [bn][s][h] (+bias), SEG/2 floats
#define OFS_Z   (4*SEG + SEG/2)         // fp32 z [b][q][n][h] = 256x512

__device__ __forceinline__ short f2bf(float x) {
  unsigned u = __float_as_uint(x);
  u += 0x7fff + ((u >> 16) & 1);        // round-to-nearest-even
  return (short)(u >> 16);
}

// ---------------------------------------------------------------------------
// Kernel A: 5 projections, 16-row tiles (4x W reuse vs R2).
// grid = proj(5) x head(8) x rowtile(16); 256 thr = 64 h x 4 wave-slots,
// each thread 4 rows -> 4 FMA per W load.
// ---------------------------------------------------------------------------
__global__ __launch_bounds__(256) void proj_kernel(
    const float* __restrict__ x,   const float* __restrict__ Wk1,
    const float* __restrict__ Wk2, const float* __restrict__ Wq,
    const float* __restrict__ Wv12,const float* __restrict__ bk1,
    const float* __restrict__ bk2, const float* __restrict__ bq,
    float* __restrict__ ws)
{
  int t = blockIdx.x;
  int rt = t & 15; t >>= 4;           // 16-row tile of the 256 (b,s) rows
  int n = t & 7;   t >>= 3;
  int proj = t;                       // 0..4
  int h  = threadIdx.x & 63;
  int wv = threadIdx.x >> 6;

  const float* W;
  switch (proj) {
    case 0:  W = Wk1 + n*DM*DH;  break;
    case 1:  W = Wk2 + n*DM*DH;  break;
    case 2:  W = Wq  + n*DM*DH;  break;
    case 3:  W = Wv12 + n*2*DM*DH;  break;
    default: W = Wv12 + n*2*DM*DH + DM*DH;  break;
  }

  __shared__ float xs[16][DM];
  for (int v = threadIdx.x; v < 2048; v += 256) {   // 16x512 floats via float4
    int r = v >> 7, c = (v & 127) * 4;
    *(float4*)&xs[r][c] = *(const float4*)&x[(size_t)(rt*16 + r)*DM + c];
  }
  __syncthreads();

  float a0=0.f, a1=0.f, a2=0.f, a3=0.f;
  #pragma unroll 8
  for (int d = 0; d < DM; ++d) {
    float w = W[d*DH + h];
    a0 = fmaf(xs[wv   ][d], w, a0);
    a1 = fmaf(xs[wv+ 4][d], w, a1);
    a2 = fmaf(xs[wv+ 8][d], w, a2);
    a3 = fmaf(xs[wv+12][d], w, a3);
  }

  float accs[4] = {a0, a1, a2, a3};
  #pragma unroll
  for (int r = 0; r < 4; ++r) {
    int row = rt*16 + wv + 4*r;       // global (b,s) row
    int b = row >> 7, s = row & 127;
    int bn = b*NH + n;
    size_t o = (size_t)(bn*TS + s)*DH + h;
    float acc = accs[r];
    switch (proj) {
      case 0: ws[OFS_K1 + o] = acc + bk1[n*DH + h]; break;
      case 1: ((unsigned short*)(ws + OFS_K2B))[o] =
                (unsigned short)f2bf(acc + bk2[n*DH + h]); break;
      case 2: ws[OFS_Q + o] = acc + bq[n*DH + h]; break;
      case 3: ws[OFS_VA + o] = acc; break;
      default: ws[OFS_VB + o] = acc; break;
    }
  }
}

// ---------------------------------------------------------------------------
// Kernel B: per (bn,q). Ahat = k1 o q_row -> S = Ahat @ k2^T (MFMA) ->
// P = exp(S/64) masked s<t<q -> row/col marginals R,C via shuffles ->
// z = (R.va + C.vb)/D + b_V12. No pair domain, no partials.
// 256 thr = 4 waves; wave wv owns s rows [32wv,32wv+32).
// ---------------------------------------------------------------------------
__global__ __launch_bounds__(256) void attn_kernel(
    const float* __restrict__ ws, const float* __restrict__ bv12,
    float* __restrict__ z)
{
  int q  = blockIdx.x & 127;
  int bn = blockIdx.x >> 7;
  int tid = threadIdx.x;
  int wv = tid >> 6, ln = tid & 63, q4 = ln >> 4, l15 = ln & 15;
  int b = bn >> 3, n = bn & 7;
  float* zrow = z + ((b*TS + q)*NH + n)*DH;

  if (q < 2) {                        // all masked; sink takes weight, vf(sink)=0
    if (tid < DH) zrow[tid] = 0.f;
    return;
  }

  __shared__ __align__(16) short Ah[128][72];   // k1 o q, bf16, padded rows
  __shared__ __align__(16) short K2s[128][72];  // k2 bf16, padded
  __shared__ float qs[64];
  __shared__ float Rs[128];
  __shared__ float Cp[4][128];                  // per-wave column partials
  __shared__ float Ds;
  __shared__ float zpart[4][64];

  if (tid < 64) qs[tid] = ws[OFS_Q + (size_t)(bn*TS + q)*DH + tid];
  ((float*)Cp)[tid] = 0.f; ((float*)Cp)[tid + 256] = 0.f;
  __syncthreads();

  const float* k1 = ws + OFS_K1 + (size_t)bn*TS*DH;
  const unsigned short* k2 = (const unsigned short*)(ws + OFS_K2B) + (size_t)bn*TS*DH;
  for (int i = tid; i < TS*DH; i += 256) {      // build Ahat (coalesced)
    int s = i >> 6, h = i & 63;
    Ah[s][h] = f2bf(k1[i] * qs[h]);
  }
  for (int v = tid; v < 1024; v += 256) {       // stage k2, 16B chunks
    int s = v >> 3, c = (v & 7) * 8;
    *(short8*)&K2s[s][c] = *(const short8*)&k2[s*DH + c];
  }
  __syncthreads();

  short8 afr[2][2];                             // A-frags for wave's 2 s-tiles
  #pragma unroll
  for (int si = 0; si < 2; ++si) {
    int m = (2*wv + si)*16 + l15;
    afr[si][0] = *(const short8*)&Ah[m][q4*8];
    afr[si][1] = *(const short8*)&Ah[m][q4*8 + 32];
  }

  float rsum[2][4] = {{0.f,0.f,0.f,0.f},{0.f,0.f,0.f,0.f}};
  for (int tt = 0; tt < 8; ++tt) {
    int t0 = tt*16;
    if (t0 >= q) break;                         // uniform: later tiles fully masked
    if (32*wv >= min(t0 + 15, q - 1)) continue; // wave's s rows all masked for this tile
    int tg = t0 + l15;
    short8 bfr0 = *(const short8*)&K2s[tg][q4*8];
    short8 bfr1 = *(const short8*)&K2s[tg][q4*8 + 32];
    float csum = 0.f;
    #pragma unroll
    for (int si = 0; si < 2; ++si) {
      floatx4 c = (floatx4){0.f,0.f,0.f,0.f};
      c = __builtin_amdgcn_mfma_f32_16x16x32_bf16(afr[si][0], bfr0, c, 0,0,0);
      c = __builtin_amdgcn_mfma_f32_16x16x32_bf16(afr[si][1], bfr1, c, 0,0,0);
      #pragma unroll
      for (int rg = 0; rg < 4; ++rg) {          // C layout: row=q4*4+rg, col=l15
        int s = (2*wv + si)*16 + q4*4 + rg;
        float e = (s < tg && tg < q) ? __expf(c[rg] * 0.015625f) : 0.f;
        rsum[si][rg] += e;
        csum += e;
      }
    }
    csum += __shfl_xor(csum, 16, 64);           // sum over the 4 q4 row-groups
    csum += __shfl_xor(csum, 32, 64);
    if (q4 == 0) Cp[wv][tg] = csum;             // distinct t per tt: plain store
  }

  #pragma unroll
  for (int si = 0; si < 2; ++si)
    #pragma unroll
    for (int rg = 0; rg < 4; ++rg) {            // row sums: reduce over l15
      float v = rsum[si][rg];
      v += __shfl_xor(v, 1, 64);
      v += __shfl_xor(v, 2, 64);
      v += __shfl_xor(v, 4, 64);
      v += __shfl_xor(v, 8, 64);
      if (l15 == 0) Rs[(2*wv + si)*16 + q4*4 + rg] = v;
    }
  __syncthreads();

  if (tid < 64) {                               // D = sum R (sink adds 0)
    float v = Rs[tid] + Rs[tid + 64];
    for (int off = 32; off > 0; off >>= 1) v += __shfl_down(v, off, 64);
    if (tid == 0) Ds = v;
  }
  __syncthreads();

  const float* va = ws + OFS_VA + (size_t)bn*TS*DH;
  const float* vb = ws + OFS_VB + (size_t)bn*TS*DH;
  int g = tid >> 6, h = tid & 63;
  float acc = 0.f;
  for (int s = g; s < q - 1; s += 4) acc = fmaf(Rs[s], va[s*DH + h], acc);
  for (int t = g ? g : 4; t < q; t += 4) {      // C[0]=0 always; skip t=0
    float cv = Cp[0][t] + Cp[1][t] + Cp[2][t] + Cp[3][t];
    acc = fmaf(cv, vb[t*DH + h], acc);
  }
  zpart[g][h] = acc;
  __syncthreads();
  if (tid < 64) {
    float zv = (zpart[0][tid] + zpart[1][tid] + zpart[2][tid] + zpart[3][tid]) / Ds;
    zrow[tid] = zv + bv12[n*DH + tid];
  }
}

// ---------------------------------------------------------------------------
// Kernel C: out(256x512) = Z @ W_O + b_O. 256 blocks (2 rows x 256 cols).
// ---------------------------------------------------------------------------
__global__ __launch_bounds__(256) void out_kernel(
    const float* __restrict__ zin, const float* __restrict__ Wo,
    const float* __restrict__ bo, float* __restrict__ out)
{
  int rt = blockIdx.x >> 1, ch = blockIdx.x & 1;
  int col = ch*256 + threadIdx.x;
  __shared__ float zs[2][512];
  {
    int v = threadIdx.x;                        // 1024 floats via float4
    int r = v >> 7, c = (v & 127) * 4;
    *(float4*)&zs[r][c] = *(const float4*)&zin[(size_t)(rt*2 + r)*512 + c];
  }
  __syncthreads();

  float a0 = 0.f, a1 = 0.f;
  #pragma unroll 8
  for (int k = 0; k < 512; ++k) {
    float w = Wo[k*512 + col];
    a0 = fmaf(zs[0][k], w, a0);
    a1 = fmaf(zs[1][k], w, a1);
  }
  out[(size_t)(rt*2    )*512 + col] = a0 + bo[col];
  out[(size_t)(rt*2 + 1)*512 + col] = a1 + bo[col];
}

extern "C" void kernel_launch(void* const* d_in, const int* in_sizes, int n_in,
                              void* d_out, int out_size, void* d_ws, size_t ws_size,
                              hipStream_t stream)
{
  const float* x    = (const float*)d_in[0];
  const float* Wk1  = (const float*)d_in[1];
  const float* Wk2  = (const float*)d_in[2];
  const float* Wq   = (const float*)d_in[3];
  const float* Wv12 = (const float*)d_in[4];
  const float* Wo   = (const float*)d_in[5];
  const float* bk1  = (const float*)d_in[6];
  const float* bk2  = (const float*)d_in[7];
  const float* bq   = (const float*)d_in[8];
  const float* bv12 = (const float*)d_in[9];
  const float* bo   = (const float*)d_in[10];
  float* out = (float*)d_out;
  float* ws  = (float*)d_ws;    // 2.88 MB

  proj_kernel<<<5*NH*16, 256, 0, stream>>>(x, Wk1, Wk2, Wq, Wv12, bk1, bk2, bq, ws);
  attn_kernel<<<BN*TS, 256, 0, stream>>>(ws, bv12, ws + OFS_Z);
  out_kernel<<<256, 256, 0, stream>>>(ws + OFS_Z, Wo, bo, out);
}

// Round 4
// 154.380 us; speedup vs baseline: 1.6475x; 1.0461x over previous
//
#include <hip/hip_runtime.h>

#define BS 2
#define TS 128
#define DM 512
#define NH 8
#define DH 64
#define BN (BS*NH)            // 16

typedef __attribute__((ext_vector_type(8))) short short8;
typedef __attribute__((ext_vector_type(4))) float floatx4;

// ws layout (float element offsets). Total 5.5*SEG*4B = 2.88 MB.
#define SEG (BN*TS*DH)                  // 131072
#define OFS_K1  0                       // fp32 [bn][s][h] (+bias)
#define OFS_Q   SEG                     // fp32 [bn][s][h] (+bias)
#define OFS_VA  (2*SEG)                 // fp32 [bn][s][h]
#define OFS_VB  (3*SEG)                 // fp32 [bn][s][h]
#define OFS_K2B (4*SEG)                 // bf16 [bn][s][h] (+bias), SEG/2 floats
#define OFS_Z   (4*SEG + SEG/2)         // fp32 z [b][q][n][h] = 256x512

__device__ __forceinline__ unsigned short f2bf(float x) {
  unsigned u = __float_as_uint(x);
  u += 0x7fff + ((u >> 16) & 1);        // round-to-nearest-even
  return (unsigned short)(u >> 16);
}

// ---------------------------------------------------------------------------
// Kernel A: 5 projections via bf16 MFMA. Block = (proj, n, rowtile of 64).
// x-tile and W staged in LDS ONCE per block (W transposed to [n][k] for
// contiguous b-frags). 160 blocks, 256 thr = 4 waves (wave = m-tile of 16).
// ---------------------------------------------------------------------------
__global__ __launch_bounds__(256) void proj_kernel(
    const float* __restrict__ x,   const float* __restrict__ Wk1,
    const float* __restrict__ Wk2, const float* __restrict__ Wq,
    const float* __restrict__ Wv12,const float* __restrict__ bk1,
    const float* __restrict__ bk2, const float* __restrict__ bq,
    float* __restrict__ ws)
{
  int t = blockIdx.x;
  int rt = t & 3; t >>= 2;            // 4 rowtiles of 64 (b,s)-rows
  int n  = t & 7; t >>= 3;
  int proj = t;                       // 0..4
  int tid = threadIdx.x;
  int wv = tid >> 6, ln = tid & 63, q4 = ln >> 4, l15 = ln & 15;

  const float* W;
  switch (proj) {
    case 0:  W = Wk1 + n*DM*DH;  break;
    case 1:  W = Wk2 + n*DM*DH;  break;
    case 2:  W = Wq  + n*DM*DH;  break;
    case 3:  W = Wv12 + n*2*DM*DH;  break;
    default: W = Wv12 + n*2*DM*DH + DM*DH;  break;
  }

  __shared__ __align__(16) short xb [64][520];   // x rows, bf16, 1040B rows (16B-mult, bank-rotated)
  __shared__ __align__(16) short wbt[64][520];   // W transposed [h][k]

  for (int v = tid; v < 8192; v += 256) {        // stage x: 64x512 via float4
    int r = v >> 7, c = (v & 127) * 4;
    float4 xv = *(const float4*)&x[(size_t)(rt*64 + r)*DM + c];
    uint2 pk;
    pk.x = (unsigned)f2bf(xv.x) | ((unsigned)f2bf(xv.y) << 16);
    pk.y = (unsigned)f2bf(xv.z) | ((unsigned)f2bf(xv.w) << 16);
    *(uint2*)&xb[r][c] = pk;
  }
  {                                              // stage W transposed
    int nn = ln, kc8 = wv;
    for (int p = 0; p < 16; ++p) {
      int k0 = p*32 + kc8*8;
      unsigned short tmp[8];
      #pragma unroll
      for (int jj = 0; jj < 8; ++jj) tmp[jj] = f2bf(W[(k0 + jj)*DH + nn]);
      uint4 pk;
      pk.x = tmp[0] | ((unsigned)tmp[1] << 16);
      pk.y = tmp[2] | ((unsigned)tmp[3] << 16);
      pk.z = tmp[4] | ((unsigned)tmp[5] << 16);
      pk.w = tmp[6] | ((unsigned)tmp[7] << 16);
      *(uint4*)&wbt[nn][k0] = pk;
    }
  }
  __syncthreads();

  short8 afr[16];                                // all K-chunks of wave's m-row
  #pragma unroll
  for (int kc = 0; kc < 16; ++kc)
    afr[kc] = *(const short8*)&xb[wv*16 + l15][kc*32 + q4*8];

  floatx4 acc[4];
  #pragma unroll
  for (int nt = 0; nt < 4; ++nt) {
    floatx4 c = (floatx4){0.f,0.f,0.f,0.f};
    #pragma unroll
    for (int kc = 0; kc < 16; ++kc) {
      short8 bfr = *(const short8*)&wbt[nt*16 + l15][kc*32 + q4*8];
      c = __builtin_amdgcn_mfma_f32_16x16x32_bf16(afr[kc], bfr, c, 0,0,0);
    }
    acc[nt] = c;
  }

  #pragma unroll
  for (int nt = 0; nt < 4; ++nt) {
    int col = nt*16 + l15;
    float bias = 0.f;
    if (proj == 0) bias = bk1[n*DH + col];
    else if (proj == 1) bias = bk2[n*DH + col];
    else if (proj == 2) bias = bq[n*DH + col];
    #pragma unroll
    for (int r = 0; r < 4; ++r) {
      int row = rt*64 + wv*16 + q4*4 + r;        // C layout: row=(l>>4)*4+reg
      int b = row >> 7, s = row & 127;
      size_t o = (size_t)((b*NH + n)*TS + s)*DH + col;
      float v = acc[nt][r] + bias;
      switch (proj) {
        case 0: ws[OFS_K1 + o] = v; break;
        case 1: ((unsigned short*)(ws + OFS_K2B))[o] = f2bf(v); break;
        case 2: ws[OFS_Q + o] = v; break;
        case 3: ws[OFS_VA + o] = v; break;
        default: ws[OFS_VB + o] = v; break;
      }
    }
  }
}

// ---------------------------------------------------------------------------
// Kernel B: q-tiled trittention. Block = (bn, j); handles q = j+16*qi,
// qi=0..7 (stride-16 q's balance the q^2 workload). k1/va/vb pinned in
// REGISTERS (1 block/CU -> ~512 VGPR budget), k2 in LDS once per block.
// Per q: Ah=k1*qv -> S=Ah@k2^T (MFMA) -> exp+mask -> row/col marginals ->
// z=(R.va + C.vb)/D + b_V12.
// ---------------------------------------------------------------------------
__global__ __launch_bounds__(256) void attn_kernel(
    const float* __restrict__ ws, const float* __restrict__ bv12,
    float* __restrict__ z)
{
  int j  = blockIdx.x & 15;
  int bn = blockIdx.x >> 4;
  int tid = threadIdx.x;
  int wv = tid >> 6, ln = tid & 63, q4 = ln >> 4, l15 = ln & 15;
  int g = wv, h = ln;                            // thread owns s in {g+4i}, col h
  int b = bn >> 3, n = bn & 7;

  __shared__ __align__(16) short Ah[128][72];    // k1 o qv, bf16 (144B rows)
  __shared__ __align__(16) short K2s[128][72];   // k2 bf16
  __shared__ float qs[8][64];
  __shared__ float Rs[128];
  __shared__ float Cp[4][128];                   // per-wave col-marginal partials
  __shared__ float zpart[4][64];
  __shared__ float dpart[4];

  const float* k1g = ws + OFS_K1 + (size_t)bn*TS*DH;
  const float* vag = ws + OFS_VA + (size_t)bn*TS*DH;
  const float* vbg = ws + OFS_VB + (size_t)bn*TS*DH;
  const unsigned short* k2g = (const unsigned short*)(ws + OFS_K2B) + (size_t)bn*TS*DH;

  float k1r[32], var[32], vbr[32];               // s = g + 4i; offset = tid + 256i
  #pragma unroll
  for (int i = 0; i < 32; ++i) {
    int o = tid + 256*i;
    k1r[i] = k1g[o]; var[i] = vag[o]; vbr[i] = vbg[o];
  }
  for (int v = tid; v < 512; v += 256) {         // 8 q-rows
    int qi = v >> 6;
    qs[qi][v & 63] = ws[OFS_Q + ((size_t)bn*TS + j + 16*qi)*DH + (v & 63)];
  }
  for (int v = tid; v < 1024; v += 256) {        // k2 -> LDS (16B chunks)
    int s = v >> 3, c = (v & 7) * 8;
    *(short8*)&K2s[s][c] = *(const short8*)&k2g[s*DH + c];
  }
  __syncthreads();

  for (int qi = 0; qi < 8; ++qi) {
    int q = j + 16*qi;                           // block-uniform
    if (q < 2) {                                 // fully masked: sink takes all
      if (tid < 64) z[((size_t)(b*TS + q)*NH + n)*DH + tid] = 0.f;
      continue;
    }

    // (A) zero Cp, build Ah
    ((float*)Cp)[tid] = 0.f; ((float*)Cp)[tid + 256] = 0.f;
    float qv = qs[qi][h];
    #pragma unroll
    for (int i = 0; i < 32; ++i)
      *(unsigned short*)&Ah[g + 4*i][h] = f2bf(k1r[i] * qv);
    __syncthreads();

    // (B) S = Ah @ K2^T, exp+mask, marginals. Wave wv owns s-tiles {2wv,2wv+1}.
    short8 afr[2][2];
    #pragma unroll
    for (int si = 0; si < 2; ++si) {
      int m = (2*wv + si)*16 + l15;
      afr[si][0] = *(const short8*)&Ah[m][q4*8];
      afr[si][1] = *(const short8*)&Ah[m][q4*8 + 32];
    }
    float rsum[2][4] = {{0.f,0.f,0.f,0.f},{0.f,0.f,0.f,0.f}};
    for (int tt = 0; tt < 8; ++tt) {
      int t0 = tt*16;
      if (t0 >= q) break;                        // block-uniform
      if (32*wv >= min(t0 + 15, q - 1)) continue;// wave-uniform: all rows masked
      int tg = t0 + l15;
      short8 bfr0 = *(const short8*)&K2s[tg][q4*8];
      short8 bfr1 = *(const short8*)&K2s[tg][q4*8 + 32];
      float csum = 0.f;
      #pragma unroll
      for (int si = 0; si < 2; ++si) {
        floatx4 c = (floatx4){0.f,0.f,0.f,0.f};
        c = __builtin_amdgcn_mfma_f32_16x16x32_bf16(afr[si][0], bfr0, c, 0,0,0);
        c = __builtin_amdgcn_mfma_f32_16x16x32_bf16(afr[si][1], bfr1, c, 0,0,0);
        #pragma unroll
        for (int rg = 0; rg < 4; ++rg) {         // C: row(s)=q4*4+rg, col(t)=l15
          int s = (2*wv + si)*16 + q4*4 + rg;
          float e = (s < tg && tg < q) ? __expf(c[rg] * 0.015625f) : 0.f;
          rsum[si][rg] += e;
          csum += e;
        }
      }
      csum += __shfl_xor(csum, 16, 64);          // reduce over q4 groups
      csum += __shfl_xor(csum, 32, 64);
      if (q4 == 0) Cp[wv][tg] = csum;
    }
    #pragma unroll
    for (int si = 0; si < 2; ++si)
      #pragma unroll
      for (int rg = 0; rg < 4; ++rg) {           // row sums: reduce over l15
        float v = rsum[si][rg];
        v += __shfl_xor(v, 1, 64); v += __shfl_xor(v, 2, 64);
        v += __shfl_xor(v, 4, 64); v += __shfl_xor(v, 8, 64);
        if (l15 == 0) Rs[(2*wv + si)*16 + q4*4 + rg] = v;
      }
    __syncthreads();

    // (C) z numerator partials + D partial (Rs/Cp reads are lane-broadcast)
    float acc = 0.f, dp = 0.f;
    #pragma unroll
    for (int i = 0; i < 32; ++i) {
      int s = g + 4*i;
      float rv = Rs[s];
      float cv = Cp[0][s] + Cp[1][s] + Cp[2][s] + Cp[3][s];
      acc = fmaf(rv, var[i], acc);
      acc = fmaf(cv, vbr[i], acc);
      dp += rv;
    }
    zpart[g][h] = acc;
    if (ln == 0) dpart[g] = dp;
    __syncthreads();

    // (D) normalize + bias + store
    if (tid < 64) {
      float D = dpart[0] + dpart[1] + dpart[2] + dpart[3];
      float zv = (zpart[0][tid] + zpart[1][tid] + zpart[2][tid] + zpart[3][tid]) / D;
      z[((size_t)(b*TS + q)*NH + n)*DH + tid] = zv + bv12[n*DH + tid];
    }
  }
}

// ---------------------------------------------------------------------------
// Kernel C: out(256x512) = Z @ W_O + b_O (fp32, preserves error margin).
// ---------------------------------------------------------------------------
__global__ __launch_bounds__(256) void out_kernel(
    const float* __restrict__ zin, const float* __restrict__ Wo,
    const float* __restrict__ bo, float* __restrict__ out)
{
  int rt = blockIdx.x >> 1, ch = blockIdx.x & 1;
  int col = ch*256 + threadIdx.x;
  __shared__ float zs[2][512];
  {
    int v = threadIdx.x;
    int r = v >> 7, c = (v & 127) * 4;
    *(float4*)&zs[r][c] = *(const float4*)&zin[(size_t)(rt*2 + r)*512 + c];
  }
  __syncthreads();

  float a0 = 0.f, a1 = 0.f;
  #pragma unroll 8
  for (int k = 0; k < 512; ++k) {
    float w = Wo[k*512 + col];
    a0 = fmaf(zs[0][k], w, a0);
    a1 = fmaf(zs[1][k], w, a1);
  }
  out[(size_t)(rt*2    )*512 + col] = a0 + bo[col];
  out[(size_t)(rt*2 + 1)*512 + col] = a1 + bo[col];
}

extern "C" void kernel_launch(void* const* d_in, const int* in_sizes, int n_in,
                              void* d_out, int out_size, void* d_ws, size_t ws_size,
                              hipStream_t stream)
{
  const float* x    = (const float*)d_in[0];
  const float* Wk1  = (const float*)d_in[1];
  const float* Wk2  = (const float*)d_in[2];
  const float* Wq   = (const float*)d_in[3];
  const float* Wv12 = (const float*)d_in[4];
  const float* Wo   = (const float*)d_in[5];
  const float* bk1  = (const float*)d_in[6];
  const float* bk2  = (const float*)d_in[7];
  const float* bq   = (const float*)d_in[8];
  const float* bv12 = (const float*)d_in[9];
  const float* bo   = (const float*)d_in[10];
  float* out = (float*)d_out;
  float* ws  = (float*)d_ws;    // 2.88 MB

  proj_kernel<<<5*NH*4, 256, 0, stream>>>(x, Wk1, Wk2, Wq, Wv12, bk1, bk2, bq, ws);
  attn_kernel<<<BN*16, 256, 0, stream>>>(ws, bv12, ws + OFS_Z);
  out_kernel<<<256, 256, 0, stream>>>(ws + OFS_Z, Wo, bo, out);
}